// Round 1
// baseline (759.804 us; speedup 1.0000x reference)
//
#include <hip/hip_runtime.h>
#include <cstdint>
#include <cstddef>

// Problem dims (fixed)
#define NN 131072      // nodes
#define EE 262144      // events
#define DD 128         // memory dim
#define RR 128         // raw msg dim
#define TT 32          // time dim
// msg GEMM: K = 448 = [mem_s 128 | mem_d 128 | raw 128 | tenc_s 32 | tenc_d 32], Nout = 256
// gru GEMM: K = 256 = [aggr 128 | memory 128], Nout = 512 = [r 128 | z 128 | i_n 128 | h_n 128]

typedef __attribute__((ext_vector_type(8))) short bf16x8;
typedef __attribute__((ext_vector_type(4))) float f32x4;

__device__ __forceinline__ unsigned short f2bf(float f) {
    unsigned int u = __builtin_bit_cast(unsigned int, f);
    u += 0x7FFFu + ((u >> 16) & 1u);   // RNE; inputs are well-behaved (no NaN)
    return (unsigned short)(u >> 16);
}

__device__ __forceinline__ float sigmoidf_(float x) {
    return 1.0f / (1.0f + __expf(-x));
}
__device__ __forceinline__ float tanhf_(float x) {
    float ax = fabsf(x);
    float e = __expf(-2.0f * ax);
    float r = (1.0f - e) / (1.0f + e);
    return copysignf(r, x);
}

// ---------------- prep: pack message weight 256x448 bf16 + bias 256 ----------------
__global__ void k_prep_wmsg(const float* __restrict__ Ws, const float* __restrict__ Wd,
                            const float* __restrict__ bs, const float* __restrict__ bd,
                            unsigned short* __restrict__ Wm, float* __restrict__ bm) {
    int n = blockIdx.x;    // 0..255 output row
    int k = threadIdx.x;   // 0..447
    float v;
    if (n < 128) {
        // msg_s input order [mem_s, mem_d, raw, tenc_s] == X'[0:416]
        v = (k < 416) ? Ws[n * 416 + k] : 0.0f;
    } else {
        int m = n - 128;
        // msg_d input order [mem_d, mem_s, raw, tenc_d]; remap to X' basis
        if (k < 128)       v = Wd[m * 416 + 128 + k];      // X' mem_s <- Wd block 1
        else if (k < 256)  v = Wd[m * 416 + (k - 128)];    // X' mem_d <- Wd block 0
        else if (k < 384)  v = Wd[m * 416 + k];            // raw
        else if (k < 416)  v = 0.0f;                       // tenc_s unused by msg_d
        else               v = Wd[m * 416 + 384 + (k - 416)]; // tenc_d
    }
    Wm[n * 448 + k] = f2bf(v);
    if (blockIdx.x == 0 && k < 256) bm[k] = (k < 128) ? bs[k] : bd[k - 128];
}

// ---------------- prep: pack GRU weight 512x256 bf16 + bias 512 ----------------
__global__ void k_prep_wgru(const float* __restrict__ Wih, const float* __restrict__ Whh,
                            const float* __restrict__ bih, const float* __restrict__ bhh,
                            unsigned short* __restrict__ Wg, float* __restrict__ bg) {
    int j = blockIdx.x;    // 0..511 output row
    int k = threadIdx.x;   // 0..255
    float v;
    if (j < 256)       v = (k < 128) ? Wih[j * 128 + k] : Whh[j * 128 + (k - 128)]; // r,z: gi+gh
    else if (j < 384)  v = (k < 128) ? Wih[j * 128 + k] : 0.0f;                      // i_n
    else               v = (k < 128) ? 0.0f : Whh[(j - 128) * 128 + (k - 128)];      // h_n
    Wg[j * 256 + k] = f2bf(v);
    if (j == 0) {
        for (int i = k; i < 512; i += 256) {
            float b = (i < 256) ? (bih[i] + bhh[i]) : ((i < 384) ? bih[i] : bhh[i - 128]);
            bg[i] = b;
        }
    }
}

// ---------------- memory fp32 -> bf16 table ----------------
__global__ void k_memconv(const float* __restrict__ in, unsigned short* __restrict__ outp) {
    int gid = blockIdx.x * 256 + threadIdx.x;        // one float4 each
    const float4 v = ((const float4*)in)[gid];
    ushort4 o;
    o.x = f2bf(v.x); o.y = f2bf(v.y); o.z = f2bf(v.z); o.w = f2bf(v.w);
    *(ushort4*)(outp + (size_t)gid * 4) = o;
}

// ---------------- time encodings, bf16 [E,32] x2 ----------------
__global__ void k_tenc(const int* __restrict__ t, const int* __restrict__ src,
                       const int* __restrict__ dst, const int* __restrict__ lu,
                       const float* __restrict__ tw, const float* __restrict__ tb,
                       unsigned short* __restrict__ tenc_s, unsigned short* __restrict__ tenc_d) {
    int gid = blockIdx.x * 256 + threadIdx.x;   // E*64 threads
    int e = gid >> 6;
    int j = gid & 63;
    int jj = j & 31;
    int node = (j < 32) ? src[e] : dst[e];
    float tr = (float)(t[e] - lu[node]);
    float ph = tr * tw[jj] + tb[jj];
    unsigned short v = f2bf(__cosf(ph));
    if (j < 32) tenc_s[(size_t)e * 32 + jj] = v;
    else        tenc_d[(size_t)e * 32 + jj] = v;
}

// ---------------- counts + timestamp scatter-max ----------------
__global__ void k_cnt(const int* __restrict__ src, const int* __restrict__ dst,
                      const int* __restrict__ t, int* cnt, int* lu_tmp) {
    int e = blockIdx.x * 256 + threadIdx.x;
    int s = src[e], d = dst[e], tv = t[e];
    atomicAdd(&cnt[s], 1);
    atomicAdd(&cnt[d], 1);
    atomicMax(&lu_tmp[s], tv);
    atomicMax(&lu_tmp[d], tv);
}

// ---------------- fused message GEMM + scatter-add ----------------
// block: 128 events x 256 outputs, K=448 in 14 chunks of 32. 256 thr = 4 waves.
// wave w: all 8 M-tiles x 4 N-tiles [4w..4w+3]; acc 8x4 f32x4 = 128 VGPR.
__launch_bounds__(256, 2)
__global__ void k_msg(const unsigned short* __restrict__ memb,
                      const float* __restrict__ raw,
                      const unsigned short* __restrict__ tenc_s,
                      const unsigned short* __restrict__ tenc_d,
                      const unsigned short* __restrict__ Wm,
                      const float* __restrict__ bm,
                      const int* __restrict__ src, const int* __restrict__ dst,
                      float* sums) {
    __shared__ int s_idx[128], d_idx[128];
    __shared__ __align__(16) unsigned short As[128 * 40];  // pad 32->40: 2-way banks (free)
    __shared__ __align__(16) unsigned short Bs[256 * 40];

    const int tid = threadIdx.x;
    const int e0 = blockIdx.x * 128;
    if (tid < 128) s_idx[tid] = src[e0 + tid];
    else           d_idx[tid - 128] = dst[e0 + tid - 128];
    __syncthreads();

    const int lane = tid & 63, w = tid >> 6;
    const int col0 = lane & 15, q = lane >> 4;

    f32x4 acc[8][4];
#pragma unroll
    for (int a = 0; a < 8; ++a)
#pragma unroll
        for (int b = 0; b < 4; ++b)
#pragma unroll
            for (int i = 0; i < 4; ++i) acc[a][b][i] = 0.0f;

    for (int c = 0; c < 14; ++c) {
        // B chunk: W' rows 0..255, k cols [32c,32c+32)
#pragma unroll
        for (int i = 0; i < 4; ++i) {
            int lin = tid + 256 * i;          // 0..1023
            int row = lin >> 2, seg = lin & 3;
            bf16x8 v = *(const bf16x8*)(Wm + (size_t)row * 448 + c * 32 + seg * 8);
            *(bf16x8*)&Bs[row * 40 + seg * 8] = v;
        }
        // A chunk
        if (c < 8) {
#pragma unroll
            for (int i = 0; i < 2; ++i) {
                int lin = tid + 256 * i;      // 0..511
                int row = lin >> 2, seg = lin & 3;
                int node = (c < 4) ? s_idx[row] : d_idx[row];
                bf16x8 v = *(const bf16x8*)(memb + (size_t)node * 128 + (c & 3) * 32 + seg * 8);
                *(bf16x8*)&As[row * 40 + seg * 8] = v;
            }
        } else if (c < 12) {
#pragma unroll
            for (int i = 0; i < 4; ++i) {
                int lin = tid + 256 * i;      // 0..1023
                int row = lin >> 3, seg = lin & 7;
                const float4 v = *(const float4*)(raw + (size_t)(e0 + row) * 128 + (c - 8) * 32 + seg * 4);
                unsigned short* p = &As[row * 40 + seg * 4];
                p[0] = f2bf(v.x); p[1] = f2bf(v.y); p[2] = f2bf(v.z); p[3] = f2bf(v.w);
            }
        } else {
            const unsigned short* tptr = (c == 12) ? tenc_s : tenc_d;
#pragma unroll
            for (int i = 0; i < 2; ++i) {
                int lin = tid + 256 * i;
                int row = lin >> 2, seg = lin & 3;
                bf16x8 v = *(const bf16x8*)(tptr + (size_t)(e0 + row) * 32 + seg * 8);
                *(bf16x8*)&As[row * 40 + seg * 8] = v;
            }
        }
        __syncthreads();

        bf16x8 afr[8], bfr[4];
#pragma unroll
        for (int mt = 0; mt < 8; ++mt)
            afr[mt] = *(const bf16x8*)&As[(mt * 16 + col0) * 40 + q * 8];
#pragma unroll
        for (int nl = 0; nl < 4; ++nl)
            bfr[nl] = *(const bf16x8*)&Bs[((w * 4 + nl) * 16 + col0) * 40 + q * 8];
#pragma unroll
        for (int mt = 0; mt < 8; ++mt)
#pragma unroll
            for (int nl = 0; nl < 4; ++nl)
                acc[mt][nl] = __builtin_amdgcn_mfma_f32_16x16x32_bf16(afr[mt], bfr[nl], acc[mt][nl], 0, 0, 0);
        __syncthreads();
    }

    // epilogue: bias + relu + scatter-add into sums (C/D layout: col=lane&15, row=q*4+reg)
#pragma unroll
    for (int nl = 0; nl < 4; ++nl) {
        int j = (w * 4 + nl) * 16 + col0;
        float bv = bm[j];
        int feat = j & 127;
        bool is_s = j < 128;
#pragma unroll
        for (int mt = 0; mt < 8; ++mt) {
#pragma unroll
            for (int r = 0; r < 4; ++r) {
                int ev = mt * 16 + q * 4 + r;
                float v = acc[mt][nl][r] + bv;
                v = fmaxf(v, 0.0f);
                int node = is_s ? s_idx[ev] : d_idx[ev];
                atomicAdd(&sums[(size_t)node * 128 + feat], v);
            }
        }
    }
}

// ---------------- GRU GEMM + gates ----------------
// block: 64 nodes x 512 outputs, K=256 in 8 chunks. wave w covers feats [32w,32w+32)
// for all 4 gates: N-tile nt = 8*g + 2*w + fh. NOTE: sums aliases out (d_out); reads
// happen before writes and rows are block-disjoint, so no __restrict__ on them.
__launch_bounds__(256, 2)
__global__ void k_gru(const float* sums, const int* __restrict__ cnt,
                      const float* __restrict__ memory,
                      const unsigned short* __restrict__ Wg,
                      const float* __restrict__ bg,
                      float* out) {
    __shared__ __align__(16) unsigned short Xs[64 * 264];  // 256 + 8 pad
    __shared__ __align__(16) unsigned short Bs[512 * 40];

    const int tid = threadIdx.x;
    const int n0 = blockIdx.x * 64;

    // stage X2 = [aggr | memory] bf16
#pragma unroll
    for (int i = 0; i < 16; ++i) {
        int lin = tid + 256 * i;          // 0..4095
        int row = lin >> 6, seg = lin & 63;
        int node = n0 + row;
        float4 v;
        if (seg < 32) {
            v = *(const float4*)(sums + (size_t)node * 128 + seg * 4);
            int cn = cnt[node];
            float inv = 1.0f / (float)(cn > 1 ? cn : 1);
            v.x *= inv; v.y *= inv; v.z *= inv; v.w *= inv;
        } else {
            v = *(const float4*)(memory + (size_t)node * 128 + (seg - 32) * 4);
        }
        unsigned short* p = &Xs[row * 264 + seg * 4];
        p[0] = f2bf(v.x); p[1] = f2bf(v.y); p[2] = f2bf(v.z); p[3] = f2bf(v.w);
    }

    const int lane = tid & 63, w = tid >> 6;
    const int col0 = lane & 15, q = lane >> 4;

    f32x4 acc[4][4][2];   // [mt][gate][fh]
#pragma unroll
    for (int a = 0; a < 4; ++a)
#pragma unroll
        for (int g = 0; g < 4; ++g)
#pragma unroll
            for (int f = 0; f < 2; ++f)
#pragma unroll
                for (int i = 0; i < 4; ++i) acc[a][g][f][i] = 0.0f;

    for (int c = 0; c < 8; ++c) {
#pragma unroll
        for (int i = 0; i < 8; ++i) {
            int lin = tid + 256 * i;      // 0..2047
            int row = lin >> 2, seg = lin & 3;
            bf16x8 v = *(const bf16x8*)(Wg + (size_t)row * 256 + c * 32 + seg * 8);
            *(bf16x8*)&Bs[row * 40 + seg * 8] = v;
        }
        __syncthreads();

        bf16x8 afr[4], bfr[4][2];
#pragma unroll
        for (int mt = 0; mt < 4; ++mt)
            afr[mt] = *(const bf16x8*)&Xs[(mt * 16 + col0) * 264 + c * 32 + q * 8];
#pragma unroll
        for (int g = 0; g < 4; ++g)
#pragma unroll
            for (int fh = 0; fh < 2; ++fh) {
                int nt = 8 * g + 2 * w + fh;
                bfr[g][fh] = *(const bf16x8*)&Bs[(nt * 16 + col0) * 40 + q * 8];
            }
#pragma unroll
        for (int mt = 0; mt < 4; ++mt)
#pragma unroll
            for (int g = 0; g < 4; ++g)
#pragma unroll
                for (int fh = 0; fh < 2; ++fh)
                    acc[mt][g][fh] = __builtin_amdgcn_mfma_f32_16x16x32_bf16(afr[mt], bfr[g][fh], acc[mt][g][fh], 0, 0, 0);
        __syncthreads();
    }

    // epilogue: gates + blend, coalesced writes
#pragma unroll
    for (int fh = 0; fh < 2; ++fh) {
        int feat = w * 32 + fh * 16 + col0;
        float b_r = bg[feat], b_z = bg[128 + feat], b_in = bg[256 + feat], b_hn = bg[384 + feat];
#pragma unroll
        for (int mt = 0; mt < 4; ++mt) {
#pragma unroll
            for (int r = 0; r < 4; ++r) {
                int node = n0 + mt * 16 + q * 4 + r;
                float rr = sigmoidf_(acc[mt][0][fh][r] + b_r);
                float zz = sigmoidf_(acc[mt][1][fh][r] + b_z);
                float nn = tanhf_((acc[mt][2][fh][r] + b_in) + rr * (acc[mt][3][fh][r] + b_hn));
                float h = memory[(size_t)node * 128 + feat];
                out[(size_t)node * 128 + feat] = (1.0f - zz) * nn + zz * h;
            }
        }
    }
}

// ---------------- last_update -> float output ----------------
__global__ void k_lu(const int* __restrict__ lu_tmp, float* __restrict__ outp) {
    int i = blockIdx.x * 256 + threadIdx.x;
    outp[i] = (float)lu_tmp[i];
}

extern "C" void kernel_launch(void* const* d_in, const int* in_sizes, int n_in,
                              void* d_out, int out_size, void* d_ws, size_t ws_size,
                              hipStream_t stream) {
    const float* memory = (const float*)d_in[0];
    const float* raw    = (const float*)d_in[1];
    const float* tw     = (const float*)d_in[2];
    const float* tb     = (const float*)d_in[3];
    const float* Wms    = (const float*)d_in[4];
    const float* bms    = (const float*)d_in[5];
    const float* Wmd    = (const float*)d_in[6];
    const float* bmd    = (const float*)d_in[7];
    const float* Wih    = (const float*)d_in[8];
    const float* Whh    = (const float*)d_in[9];
    const float* bih    = (const float*)d_in[10];
    const float* bhh    = (const float*)d_in[11];
    const int* src = (const int*)d_in[12];
    const int* dst = (const int*)d_in[13];
    const int* t   = (const int*)d_in[14];
    const int* lu  = (const int*)d_in[15];

    char* ws = (char*)d_ws;
    size_t off = 0;
    unsigned short* memb   = (unsigned short*)(ws + off); off += (size_t)NN * 128 * 2;  // 32 MB
    unsigned short* tenc_s = (unsigned short*)(ws + off); off += (size_t)EE * 32 * 2;   // 16 MB
    unsigned short* tenc_d = (unsigned short*)(ws + off); off += (size_t)EE * 32 * 2;   // 16 MB
    int* cnt               = (int*)(ws + off);            off += (size_t)NN * 4;
    int* lu_tmp            = (int*)(ws + off);            off += (size_t)NN * 4;
    unsigned short* Wm     = (unsigned short*)(ws + off); off += 256 * 448 * 2;
    float* bm              = (float*)(ws + off);          off += 256 * 4;
    unsigned short* Wg     = (unsigned short*)(ws + off); off += 512 * 256 * 2;
    float* bg              = (float*)(ws + off);          off += 512 * 4;

    float* out  = (float*)d_out;
    float* sums = out;   // alias: sums lives in d_out[0 : N*128), overwritten by k_gru

    hipMemsetAsync(out, 0, (size_t)NN * 128 * 4, stream);
    hipMemsetAsync(cnt, 0, (size_t)NN * 4, stream);
    hipMemsetAsync(lu_tmp, 0, (size_t)NN * 4, stream);

    k_prep_wmsg<<<256, 448, 0, stream>>>(Wms, Wmd, bms, bmd, Wm, bm);
    k_prep_wgru<<<512, 256, 0, stream>>>(Wih, Whh, bih, bhh, Wg, bg);
    k_memconv<<<(NN * 128 / 4) / 256, 256, 0, stream>>>(memory, memb);
    k_tenc<<<(EE * 64) / 256, 256, 0, stream>>>(t, src, dst, lu, tw, tb, tenc_s, tenc_d);
    k_cnt<<<EE / 256, 256, 0, stream>>>(src, dst, t, cnt, lu_tmp);
    k_msg<<<EE / 128, 256, 0, stream>>>(memb, raw, tenc_s, tenc_d, Wm, bm, src, dst, sums);
    k_gru<<<NN / 64, 256, 0, stream>>>(sums, cnt, memory, Wg, bg, out);
    k_lu<<<NN / 256, 256, 0, stream>>>(lu_tmp, out + (size_t)NN * 128);
}

// Round 2
// 623.873 us; speedup vs baseline: 1.2179x; 1.2179x over previous
//
#include <hip/hip_runtime.h>
#include <cstdint>
#include <cstddef>

// Problem dims (fixed)
#define NN 131072      // nodes
#define EE 262144      // events
#define DD 128         // memory dim
// msg GEMM: K = 448 = [mem_s 128 | mem_d 128 | raw 128 | tenc_s 32 | tenc_d 32], Nout = 256
// gru GEMM: K = 256 = [aggr 128 | memory 128], Nout = 512 = [r 128 | z 128 | i_n 128 | h_n 128]

typedef __attribute__((ext_vector_type(8))) short bf16x8;
typedef __attribute__((ext_vector_type(4))) float f32x4;

__device__ __forceinline__ unsigned short f2bf(float f) {
    unsigned int u = __builtin_bit_cast(unsigned int, f);
    u += 0x7FFFu + ((u >> 16) & 1u);   // RNE
    return (unsigned short)(u >> 16);
}
__device__ __forceinline__ float bf2f(unsigned short s) {
    unsigned int u = ((unsigned int)s) << 16;
    return __builtin_bit_cast(float, u);
}
__device__ __forceinline__ float sigmoidf_(float x) { return 1.0f / (1.0f + __expf(-x)); }
__device__ __forceinline__ float tanhf_(float x) {
    float ax = fabsf(x);
    float e = __expf(-2.0f * ax);
    return copysignf((1.0f - e) / (1.0f + e), x);
}

// ---------------- prep: pack message weight 256x448 bf16 + bias 256 ----------------
__global__ void k_prep_wmsg(const float* __restrict__ Ws, const float* __restrict__ Wd,
                            const float* __restrict__ bs, const float* __restrict__ bd,
                            unsigned short* __restrict__ Wm, float* __restrict__ bm) {
    int n = blockIdx.x;    // 0..255 output row
    int k = threadIdx.x;   // 0..447
    float v;
    if (n < 128) {
        v = (k < 416) ? Ws[n * 416 + k] : 0.0f;            // [mem_s, mem_d, raw, tenc_s]
    } else {
        int m = n - 128;
        if (k < 128)       v = Wd[m * 416 + 128 + k];      // X' mem_s <- Wd block 1
        else if (k < 256)  v = Wd[m * 416 + (k - 128)];    // X' mem_d <- Wd block 0
        else if (k < 384)  v = Wd[m * 416 + k];            // raw
        else if (k < 416)  v = 0.0f;                       // tenc_s unused by msg_d
        else               v = Wd[m * 416 + 384 + (k - 416)]; // tenc_d
    }
    Wm[n * 448 + k] = f2bf(v);
    if (blockIdx.x == 0 && k < 256) bm[k] = (k < 128) ? bs[k] : bd[k - 128];
}

// ---------------- prep: pack GRU weight 512x256 bf16 + bias 512 ----------------
__global__ void k_prep_wgru(const float* __restrict__ Wih, const float* __restrict__ Whh,
                            const float* __restrict__ bih, const float* __restrict__ bhh,
                            unsigned short* __restrict__ Wg, float* __restrict__ bg) {
    int j = blockIdx.x;    // 0..511 output row
    int k = threadIdx.x;   // 0..255
    float v;
    if (j < 256)       v = (k < 128) ? Wih[j * 128 + k] : Whh[j * 128 + (k - 128)]; // r,z: gi+gh
    else if (j < 384)  v = (k < 128) ? Wih[j * 128 + k] : 0.0f;                      // i_n
    else               v = (k < 128) ? 0.0f : Whh[(j - 128) * 128 + (k - 128)];      // h_n
    Wg[j * 256 + k] = f2bf(v);
    if (j == 0) {
        for (int i = k; i < 512; i += 256) {
            float b = (i < 256) ? (bih[i] + bhh[i]) : ((i < 384) ? bih[i] : bhh[i - 128]);
            bg[i] = b;
        }
    }
}

// ---------------- memory fp32 -> bf16 table ----------------
__global__ void k_memconv(const float* __restrict__ in, unsigned short* __restrict__ outp) {
    int gid = blockIdx.x * 256 + threadIdx.x;
    const float4 v = ((const float4*)in)[gid];
    ushort4 o;
    o.x = f2bf(v.x); o.y = f2bf(v.y); o.z = f2bf(v.z); o.w = f2bf(v.w);
    *(ushort4*)(outp + (size_t)gid * 4) = o;
}

// ---------------- t_rel per event-side ----------------
__global__ void k_trel(const int* __restrict__ t, const int* __restrict__ src,
                       const int* __restrict__ dst, const int* __restrict__ lu,
                       float* __restrict__ trel_s, float* __restrict__ trel_d) {
    int e = blockIdx.x * 256 + threadIdx.x;
    int tv = t[e];
    trel_s[e] = (float)(tv - lu[src[e]]);
    trel_d[e] = (float)(tv - lu[dst[e]]);
}

// ---------------- counts + timestamp scatter-max ----------------
__global__ void k_cnt(const int* __restrict__ src, const int* __restrict__ dst,
                      const int* __restrict__ t, int* cnt, int* lu_tmp) {
    int e = blockIdx.x * 256 + threadIdx.x;
    int s = src[e], d = dst[e], tv = t[e];
    atomicAdd(&cnt[s], 1);
    atomicAdd(&cnt[d], 1);
    atomicMax(&lu_tmp[s], tv);
    atomicMax(&lu_tmp[d], tv);
}

// ---------------- CSR scan: 3 stages ----------------
__global__ void k_scan1(const int* __restrict__ cnt, int* __restrict__ bsum) {
    __shared__ int red[256];
    int tid = threadIdx.x;
    red[tid] = cnt[blockIdx.x * 256 + tid];
    __syncthreads();
    for (int s = 128; s > 0; s >>= 1) {
        if (tid < s) red[tid] += red[tid + s];
        __syncthreads();
    }
    if (tid == 0) bsum[blockIdx.x] = red[0];
}
__global__ void k_scan2(const int* __restrict__ bsum, int* __restrict__ boff) {
    __shared__ int sb[512];
    int tid = threadIdx.x;
    int v = bsum[tid];
    sb[tid] = v;
    __syncthreads();
    for (int d = 1; d < 512; d <<= 1) {
        int u = (tid >= d) ? sb[tid - d] : 0;
        __syncthreads();
        sb[tid] += u;
        __syncthreads();
    }
    boff[tid] = sb[tid] - v;   // exclusive
}
__global__ void k_scan3(const int* __restrict__ cnt, const int* __restrict__ boff,
                        int* __restrict__ off, int* __restrict__ cursor) {
    __shared__ int sb[256];
    int tid = threadIdx.x;
    int i = blockIdx.x * 256 + tid;
    int v = cnt[i];
    sb[tid] = v;
    __syncthreads();
    for (int d = 1; d < 256; d <<= 1) {
        int u = (tid >= d) ? sb[tid - d] : 0;
        __syncthreads();
        sb[tid] += u;
        __syncthreads();
    }
    int o = boff[blockIdx.x] + sb[tid] - v;
    off[i] = o;
    cursor[i] = o;
}
__global__ void k_fill(const int* __restrict__ src, const int* __restrict__ dst,
                       int* cursor, int* __restrict__ ids) {
    int e2 = blockIdx.x * 256 + threadIdx.x;   // 0..2E; id<E -> s-side, else d-side
    int node = (e2 < EE) ? src[e2] : dst[e2 - EE];
    int pos = atomicAdd(&cursor[node], 1);
    ids[pos] = e2;
}

// ---------------- message GEMM -> msg[2E][128] bf16 ----------------
// block: 128 events x 256 outputs, K=448 in 14 chunks of 32. 4 waves.
__launch_bounds__(256, 2)
__global__ void k_msg(const unsigned short* __restrict__ memb,
                      const float* __restrict__ raw,
                      const float* __restrict__ trel_s,
                      const float* __restrict__ trel_d,
                      const unsigned short* __restrict__ Wm,
                      const float* __restrict__ bm,
                      const int* __restrict__ src, const int* __restrict__ dst,
                      const float* __restrict__ tw, const float* __restrict__ tb,
                      unsigned short* __restrict__ msg) {
    __shared__ int s_idx[128], d_idx[128];
    __shared__ float s_tw[32], s_tb[32];
    __shared__ __align__(16) unsigned short As[128 * 40];  // stride 40: 2-way banks (free)
    __shared__ __align__(16) unsigned short Bs[256 * 40];

    const int tid = threadIdx.x;
    const int e0 = blockIdx.x * 128;
    if (tid < 128) s_idx[tid] = src[e0 + tid];
    else           d_idx[tid - 128] = dst[e0 + tid - 128];
    if (tid < 32)       s_tw[tid] = tw[tid];
    else if (tid < 64)  s_tb[tid - 32] = tb[tid - 32];
    __syncthreads();

    const int lane = tid & 63, w = tid >> 6;
    const int col0 = lane & 15, q = lane >> 4;

    f32x4 acc[8][4];
#pragma unroll
    for (int a = 0; a < 8; ++a)
#pragma unroll
        for (int b = 0; b < 4; ++b)
#pragma unroll
            for (int i = 0; i < 4; ++i) acc[a][b][i] = 0.0f;

    for (int c = 0; c < 14; ++c) {
        // B chunk
#pragma unroll
        for (int i = 0; i < 4; ++i) {
            int lin = tid + 256 * i;
            int row = lin >> 2, seg = lin & 3;
            bf16x8 v = *(const bf16x8*)(Wm + (size_t)row * 448 + c * 32 + seg * 8);
            *(bf16x8*)&Bs[row * 40 + seg * 8] = v;
        }
        // A chunk
        if (c < 8) {
#pragma unroll
            for (int i = 0; i < 2; ++i) {
                int lin = tid + 256 * i;
                int row = lin >> 2, seg = lin & 3;
                int node = (c < 4) ? s_idx[row] : d_idx[row];
                bf16x8 v = *(const bf16x8*)(memb + (size_t)node * 128 + (c & 3) * 32 + seg * 8);
                *(bf16x8*)&As[row * 40 + seg * 8] = v;
            }
        } else if (c < 12) {
#pragma unroll
            for (int i = 0; i < 4; ++i) {
                int lin = tid + 256 * i;
                int row = lin >> 3, seg = lin & 7;
                const float4 v = *(const float4*)(raw + (size_t)(e0 + row) * 128 + (c - 8) * 32 + seg * 4);
                unsigned short* p = &As[row * 40 + seg * 4];
                p[0] = f2bf(v.x); p[1] = f2bf(v.y); p[2] = f2bf(v.z); p[3] = f2bf(v.w);
            }
        } else {
            // time encodings computed on the fly
            int row = tid >> 1, half = tid & 1;
            float tr = (c == 12) ? trel_s[e0 + row] : trel_d[e0 + row];
            unsigned short* p = &As[row * 40 + half * 16];
#pragma unroll
            for (int j2 = 0; j2 < 16; ++j2) {
                int jj = half * 16 + j2;
                p[j2] = f2bf(__cosf(tr * s_tw[jj] + s_tb[jj]));
            }
        }
        __syncthreads();

        bf16x8 afr[8], bfr[4];
#pragma unroll
        for (int mt = 0; mt < 8; ++mt)
            afr[mt] = *(const bf16x8*)&As[(mt * 16 + col0) * 40 + q * 8];
#pragma unroll
        for (int nl = 0; nl < 4; ++nl)
            bfr[nl] = *(const bf16x8*)&Bs[((w * 4 + nl) * 16 + col0) * 40 + q * 8];
#pragma unroll
        for (int mt = 0; mt < 8; ++mt)
#pragma unroll
            for (int nl = 0; nl < 4; ++nl)
                acc[mt][nl] = __builtin_amdgcn_mfma_f32_16x16x32_bf16(afr[mt], bfr[nl], acc[mt][nl], 0, 0, 0);
        __syncthreads();
    }

    // epilogue: bias + relu, plain bf16 stores (C/D layout: col=lane&15, row=q*4+reg)
#pragma unroll
    for (int nl = 0; nl < 4; ++nl) {
        int j = (w * 4 + nl) * 16 + col0;
        float bv = bm[j];
        int feat = j & 127;
        size_t base = (j < 128) ? (size_t)0 : (size_t)EE * 128;
#pragma unroll
        for (int mt = 0; mt < 8; ++mt) {
#pragma unroll
            for (int r = 0; r < 4; ++r) {
                int ev = mt * 16 + q * 4 + r;
                float v = fmaxf(acc[mt][nl][r] + bv, 0.0f);
                msg[base + (size_t)(e0 + ev) * 128 + feat] = f2bf(v);
            }
        }
    }
}

// ---------------- fused CSR mean-aggregation + GRU GEMM + gates ----------------
// block: 64 nodes x 512 outputs, K=256 in 8 chunks.
__launch_bounds__(256, 2)
__global__ void k_gru(const unsigned short* __restrict__ msg,
                      const int* __restrict__ off, const int* __restrict__ cnt,
                      const int* __restrict__ ids,
                      const float* __restrict__ memory,
                      const unsigned short* __restrict__ Wg,
                      const float* __restrict__ bg,
                      float* __restrict__ out) {
    __shared__ __align__(16) unsigned short Xs[64 * 264];  // 256 + 8 pad
    __shared__ __align__(16) unsigned short Bs[512 * 40];

    const int tid = threadIdx.x;
    const int n0 = blockIdx.x * 64;

    // aggregation: 4 threads per node, 32 feats each
    {
        int g = tid >> 2, sub = tid & 3;
        int node = n0 + g;
        int beg = off[node], cn = cnt[node];
        float a[32];
#pragma unroll
        for (int i = 0; i < 32; ++i) a[i] = 0.0f;
        for (int m = 0; m < cn; ++m) {
            int id = ids[beg + m];
            const bf16x8* p = (const bf16x8*)(msg + (size_t)id * 128 + sub * 32);
#pragma unroll
            for (int s = 0; s < 4; ++s) {
                bf16x8 v = p[s];
#pragma unroll
                for (int k = 0; k < 8; ++k)
                    a[s * 8 + k] += bf2f((unsigned short)v[k]);
            }
        }
        float inv = 1.0f / (float)(cn > 1 ? cn : 1);
        unsigned short* xp = &Xs[g * 264 + sub * 32];
#pragma unroll
        for (int i = 0; i < 32; ++i) xp[i] = f2bf(a[i] * inv);
        // memory half
        const float4* mp = (const float4*)(memory + (size_t)node * 128 + sub * 32);
        unsigned short* xq = &Xs[g * 264 + 128 + sub * 32];
#pragma unroll
        for (int s = 0; s < 8; ++s) {
            float4 v = mp[s];
            xq[s * 4 + 0] = f2bf(v.x); xq[s * 4 + 1] = f2bf(v.y);
            xq[s * 4 + 2] = f2bf(v.z); xq[s * 4 + 3] = f2bf(v.w);
        }
    }

    const int lane = tid & 63, w = tid >> 6;
    const int col0 = lane & 15, q = lane >> 4;

    f32x4 acc[4][4][2];   // [mt][gate][fh]
#pragma unroll
    for (int a = 0; a < 4; ++a)
#pragma unroll
        for (int g = 0; g < 4; ++g)
#pragma unroll
            for (int f = 0; f < 2; ++f)
#pragma unroll
                for (int i = 0; i < 4; ++i) acc[a][g][f][i] = 0.0f;

    for (int c = 0; c < 8; ++c) {
#pragma unroll
        for (int i = 0; i < 8; ++i) {
            int lin = tid + 256 * i;
            int row = lin >> 2, seg = lin & 3;
            bf16x8 v = *(const bf16x8*)(Wg + (size_t)row * 256 + c * 32 + seg * 8);
            *(bf16x8*)&Bs[row * 40 + seg * 8] = v;
        }
        __syncthreads();

        bf16x8 afr[4], bfr[4][2];
#pragma unroll
        for (int mt = 0; mt < 4; ++mt)
            afr[mt] = *(const bf16x8*)&Xs[(mt * 16 + col0) * 264 + c * 32 + q * 8];
#pragma unroll
        for (int g = 0; g < 4; ++g)
#pragma unroll
            for (int fh = 0; fh < 2; ++fh) {
                int nt = 8 * g + 2 * w + fh;
                bfr[g][fh] = *(const bf16x8*)&Bs[(nt * 16 + col0) * 40 + q * 8];
            }
#pragma unroll
        for (int mt = 0; mt < 4; ++mt)
#pragma unroll
            for (int g = 0; g < 4; ++g)
#pragma unroll
                for (int fh = 0; fh < 2; ++fh)
                    acc[mt][g][fh] = __builtin_amdgcn_mfma_f32_16x16x32_bf16(afr[mt], bfr[g][fh], acc[mt][g][fh], 0, 0, 0);
        __syncthreads();
    }

    // epilogue: gates + blend
#pragma unroll
    for (int fh = 0; fh < 2; ++fh) {
        int feat = w * 32 + fh * 16 + col0;
        float b_r = bg[feat], b_z = bg[128 + feat], b_in = bg[256 + feat], b_hn = bg[384 + feat];
#pragma unroll
        for (int mt = 0; mt < 4; ++mt) {
#pragma unroll
            for (int r = 0; r < 4; ++r) {
                int node = n0 + mt * 16 + q * 4 + r;
                float rr = sigmoidf_(acc[mt][0][fh][r] + b_r);
                float zz = sigmoidf_(acc[mt][1][fh][r] + b_z);
                float nn = tanhf_((acc[mt][2][fh][r] + b_in) + rr * (acc[mt][3][fh][r] + b_hn));
                float h = memory[(size_t)node * 128 + feat];
                out[(size_t)node * 128 + feat] = (1.0f - zz) * nn + zz * h;
            }
        }
    }
}

// ---------------- last_update -> float output ----------------
__global__ void k_lu(const int* __restrict__ lu_tmp, float* __restrict__ outp) {
    int i = blockIdx.x * 256 + threadIdx.x;
    outp[i] = (float)lu_tmp[i];
}

extern "C" void kernel_launch(void* const* d_in, const int* in_sizes, int n_in,
                              void* d_out, int out_size, void* d_ws, size_t ws_size,
                              hipStream_t stream) {
    const float* memory = (const float*)d_in[0];
    const float* raw    = (const float*)d_in[1];
    const float* tw     = (const float*)d_in[2];
    const float* tb     = (const float*)d_in[3];
    const float* Wms    = (const float*)d_in[4];
    const float* bms    = (const float*)d_in[5];
    const float* Wmd    = (const float*)d_in[6];
    const float* bmd    = (const float*)d_in[7];
    const float* Wih    = (const float*)d_in[8];
    const float* Whh    = (const float*)d_in[9];
    const float* bih    = (const float*)d_in[10];
    const float* bhh    = (const float*)d_in[11];
    const int* src = (const int*)d_in[12];
    const int* dst = (const int*)d_in[13];
    const int* t   = (const int*)d_in[14];
    const int* lu  = (const int*)d_in[15];

    char* ws = (char*)d_ws;
    size_t off_b = 0;
    unsigned short* memb = (unsigned short*)(ws + off_b); off_b += (size_t)NN * 128 * 2;       // 32 MB
    unsigned short* msg  = (unsigned short*)(ws + off_b); off_b += (size_t)2 * EE * 128 * 2;   // 128 MB
    float* trel_s        = (float*)(ws + off_b);          off_b += (size_t)EE * 4;             // 1 MB
    float* trel_d        = (float*)(ws + off_b);          off_b += (size_t)EE * 4;             // 1 MB
    int* cnt             = (int*)(ws + off_b);            off_b += (size_t)NN * 4;
    int* off             = (int*)(ws + off_b);            off_b += (size_t)NN * 4;
    int* cursor          = (int*)(ws + off_b);            off_b += (size_t)NN * 4;
    int* lu_tmp          = (int*)(ws + off_b);            off_b += (size_t)NN * 4;
    int* ids             = (int*)(ws + off_b);            off_b += (size_t)2 * EE * 4;         // 2 MB
    int* bsum            = (int*)(ws + off_b);            off_b += 512 * 4;
    int* boff            = (int*)(ws + off_b);            off_b += 512 * 4;
    unsigned short* Wm   = (unsigned short*)(ws + off_b); off_b += 256 * 448 * 2;
    float* bm            = (float*)(ws + off_b);          off_b += 256 * 4;
    unsigned short* Wg   = (unsigned short*)(ws + off_b); off_b += 512 * 256 * 2;
    float* bg            = (float*)(ws + off_b);          off_b += 512 * 4;

    float* out = (float*)d_out;

    hipMemsetAsync(cnt, 0, (size_t)NN * 4, stream);
    hipMemsetAsync(lu_tmp, 0, (size_t)NN * 4, stream);

    k_prep_wmsg<<<256, 448, 0, stream>>>(Wms, Wmd, bms, bmd, Wm, bm);
    k_prep_wgru<<<512, 256, 0, stream>>>(Wih, Whh, bih, bhh, Wg, bg);
    k_memconv<<<(NN * 128 / 4) / 256, 256, 0, stream>>>(memory, memb);
    k_trel<<<EE / 256, 256, 0, stream>>>(t, src, dst, lu, trel_s, trel_d);
    k_cnt<<<EE / 256, 256, 0, stream>>>(src, dst, t, cnt, lu_tmp);
    k_scan1<<<512, 256, 0, stream>>>(cnt, bsum);
    k_scan2<<<1, 512, 0, stream>>>(bsum, boff);
    k_scan3<<<512, 256, 0, stream>>>(cnt, boff, off, cursor);
    k_fill<<<2 * EE / 256, 256, 0, stream>>>(src, dst, cursor, ids);
    k_msg<<<EE / 128, 256, 0, stream>>>(memb, raw, trel_s, trel_d, Wm, bm, src, dst, tw, tb, msg);
    k_gru<<<NN / 64, 256, 0, stream>>>(msg, off, cnt, ids, memory, Wg, bg, out);
    k_lu<<<NN / 256, 256, 0, stream>>>(lu_tmp, out + (size_t)NN * 128);
}

// Round 3
// 579.028 us; speedup vs baseline: 1.3122x; 1.0774x over previous
//
#include <hip/hip_runtime.h>
#include <cstdint>
#include <cstddef>

// Problem dims (fixed)
#define NN 131072      // nodes
#define EE 262144      // events
// msg GEMM: K = 448 = [mem_s 128 | mem_d 128 | raw 128 | tenc_s 32 | tenc_d 32], Nout = 256
// gru GEMM: K = 256 = [aggr 128 | memory 128], Nout = 512 = [r | z | i_n | h_n]

typedef __attribute__((ext_vector_type(8))) short bf16x8;
typedef __attribute__((ext_vector_type(4))) float f32x4;

__device__ __forceinline__ unsigned short f2bf(float f) {
    unsigned int u = __builtin_bit_cast(unsigned int, f);
    u += 0x7FFFu + ((u >> 16) & 1u);   // RNE
    return (unsigned short)(u >> 16);
}
__device__ __forceinline__ float bf2f(unsigned short s) {
    unsigned int u = ((unsigned int)s) << 16;
    return __builtin_bit_cast(float, u);
}
__device__ __forceinline__ float sigmoidf_(float x) { return 1.0f / (1.0f + __expf(-x)); }
__device__ __forceinline__ float tanhf_(float x) {
    float ax = fabsf(x);
    float e = __expf(-2.0f * ax);
    return copysignf((1.0f - e) / (1.0f + e), x);
}
__device__ __forceinline__ bf16x8 pack8(const float* f) {
    bf16x8 o;
#pragma unroll
    for (int i = 0; i < 8; ++i) o[i] = (short)f2bf(f[i]);
    return o;
}

// logical W' for the fused message GEMM (256 out x 448 in)
__device__ __forceinline__ float wmsg_val(int n, int k, const float* Ws, const float* Wd) {
    if (n < 128) {
        return (k < 416) ? Ws[n * 416 + k] : 0.0f;           // [mem_s, mem_d, raw, tenc_s]
    } else {
        int m = n - 128;
        if (k < 128)       return Wd[m * 416 + 128 + k];     // X' mem_s <- Wd block 1
        else if (k < 256)  return Wd[m * 416 + (k - 128)];   // X' mem_d <- Wd block 0
        else if (k < 384)  return Wd[m * 416 + k];           // raw
        else if (k < 416)  return 0.0f;                      // tenc_s unused by msg_d
        else               return Wd[m * 416 + 384 + (k - 416)]; // tenc_d
    }
}
// logical W for the GRU GEMM (512 out x 256 in)
__device__ __forceinline__ float wgru_val(int j, int k, const float* Wih, const float* Whh) {
    if (j < 256)      return (k < 128) ? Wih[j * 128 + k] : Whh[j * 128 + (k - 128)];
    else if (j < 384) return (k < 128) ? Wih[j * 128 + k] : 0.0f;
    else              return (k < 128) ? 0.0f : Whh[(j - 128) * 128 + (k - 128)];
}

// ---------------- prep: message weight in MFMA fragment order ----------------
// Wmf[((c*16 + nt)*64 + lane)*8 + j] ; c 0..13, nt 0..15
__global__ void k_prep_msgfrag(const float* __restrict__ Ws, const float* __restrict__ Wd,
                               const float* __restrict__ bs, const float* __restrict__ bd,
                               unsigned short* __restrict__ Wmf, float* __restrict__ bm) {
    int b = blockIdx.x;              // c*16 + nt
    int c = b >> 4, nt = b & 15;
    int lane = threadIdx.x;
    int col0 = lane & 15, q = lane >> 4;
    int n = nt * 16 + col0;
    float f[8];
#pragma unroll
    for (int j = 0; j < 8; ++j) f[j] = wmsg_val(n, c * 32 + q * 8 + j, Ws, Wd);
    ((bf16x8*)Wmf)[(size_t)b * 64 + lane] = pack8(f);
    if (b == 0)
        for (int i = lane; i < 256; i += 64) bm[i] = (i < 128) ? bs[i] : bd[i - 128];
}

// ---------------- prep: GRU weight in MFMA fragment order ----------------
// Wgf[((c*32 + nt)*64 + lane)*8 + j] ; c 0..7, nt 0..31
__global__ void k_prep_grufrag(const float* __restrict__ Wih, const float* __restrict__ Whh,
                               const float* __restrict__ bih, const float* __restrict__ bhh,
                               unsigned short* __restrict__ Wgf, float* __restrict__ bg) {
    int b = blockIdx.x;              // c*32 + nt
    int c = b >> 5, nt = b & 31;
    int lane = threadIdx.x;
    int col0 = lane & 15, q = lane >> 4;
    int j0 = nt * 16 + col0;
    float f[8];
#pragma unroll
    for (int j = 0; j < 8; ++j) f[j] = wgru_val(j0, c * 32 + q * 8 + j, Wih, Whh);
    ((bf16x8*)Wgf)[(size_t)b * 64 + lane] = pack8(f);
    if (b == 0)
        for (int i = lane; i < 512; i += 64)
            bg[i] = (i < 256) ? (bih[i] + bhh[i]) : ((i < 384) ? bih[i] : bhh[i - 128]);
}

// ---------------- memory fp32 -> bf16 table ----------------
__global__ void k_memconv(const float* __restrict__ in, unsigned short* __restrict__ outp) {
    int gid = blockIdx.x * 256 + threadIdx.x;
    const float4 v = ((const float4*)in)[gid];
    ushort4 o;
    o.x = f2bf(v.x); o.y = f2bf(v.y); o.z = f2bf(v.z); o.w = f2bf(v.w);
    *(ushort4*)(outp + (size_t)gid * 4) = o;
}

// ---------------- per-event: t_rel, counts, timestamp max ----------------
__global__ void k_pre(const int* __restrict__ t, const int* __restrict__ src,
                      const int* __restrict__ dst, const int* __restrict__ lu,
                      float* __restrict__ trel_s, float* __restrict__ trel_d,
                      int* cnt, int* lu_tmp) {
    int e = blockIdx.x * 256 + threadIdx.x;
    int s = src[e], d = dst[e], tv = t[e];
    trel_s[e] = (float)(tv - lu[s]);
    trel_d[e] = (float)(tv - lu[d]);
    atomicAdd(&cnt[s], 1);
    atomicAdd(&cnt[d], 1);
    atomicMax(&lu_tmp[s], tv);
    atomicMax(&lu_tmp[d], tv);
}

// ---------------- CSR scan: 3 stages ----------------
__global__ void k_scan1(const int* __restrict__ cnt, int* __restrict__ bsum) {
    __shared__ int red[256];
    int tid = threadIdx.x;
    red[tid] = cnt[blockIdx.x * 256 + tid];
    __syncthreads();
    for (int s = 128; s > 0; s >>= 1) {
        if (tid < s) red[tid] += red[tid + s];
        __syncthreads();
    }
    if (tid == 0) bsum[blockIdx.x] = red[0];
}
__global__ void k_scan2(const int* __restrict__ bsum, int* __restrict__ boff) {
    __shared__ int sb[512];
    int tid = threadIdx.x;
    int v = bsum[tid];
    sb[tid] = v;
    __syncthreads();
    for (int d = 1; d < 512; d <<= 1) {
        int u = (tid >= d) ? sb[tid - d] : 0;
        __syncthreads();
        sb[tid] += u;
        __syncthreads();
    }
    boff[tid] = sb[tid] - v;   // exclusive
}
__global__ void k_scan3(const int* __restrict__ cnt, const int* __restrict__ boff,
                        int* __restrict__ off, int* __restrict__ cursor) {
    __shared__ int sb[256];
    int tid = threadIdx.x;
    int i = blockIdx.x * 256 + tid;
    int v = cnt[i];
    sb[tid] = v;
    __syncthreads();
    for (int d = 1; d < 256; d <<= 1) {
        int u = (tid >= d) ? sb[tid - d] : 0;
        __syncthreads();
        sb[tid] += u;
        __syncthreads();
    }
    int o = boff[blockIdx.x] + sb[tid] - v;
    off[i] = o;
    cursor[i] = o;
}
// inverse permutation: event-side -> sorted position
__global__ void k_fill(const int* __restrict__ src, const int* __restrict__ dst,
                       int* cursor, int* __restrict__ pos2) {
    int e2 = blockIdx.x * 256 + threadIdx.x;   // [0,2E): <E = s-side, >=E = d-side
    int node = (e2 < EE) ? src[e2] : dst[e2 - EE];
    pos2[e2] = atomicAdd(&cursor[node], 1);
}

// ---------------- message GEMM -> msg_sorted[2E][128] bf16 ----------------
// 128 events x 256 outputs, K=448 in 14 chunks. B frags direct from global
// (fragment-order prepack); A double-buffered in LDS; 1 barrier/chunk.
__launch_bounds__(256, 2)
__global__ void k_msg(const unsigned short* __restrict__ memb,
                      const float* __restrict__ raw,
                      const float* __restrict__ trel_s,
                      const float* __restrict__ trel_d,
                      const unsigned short* __restrict__ Wmf,
                      const float* __restrict__ bm,
                      const int* __restrict__ src, const int* __restrict__ dst,
                      const int* __restrict__ pos2,
                      const float* __restrict__ tw, const float* __restrict__ tb,
                      unsigned short* __restrict__ msg) {
    __shared__ int s_idx[128], d_idx[128], s_pos[128], d_pos[128];
    __shared__ float s_tw[32], s_tb[32];
    __shared__ __align__(16) unsigned short As[2][128 * 40];

    const int tid = threadIdx.x;
    const int e0 = blockIdx.x * 128;
    if (tid < 128) { s_idx[tid] = src[e0 + tid]; s_pos[tid] = pos2[e0 + tid]; }
    else { d_idx[tid - 128] = dst[e0 + tid - 128]; d_pos[tid - 128] = pos2[EE + e0 + tid - 128]; }
    if (tid < 32)       s_tw[tid] = tw[tid];
    else if (tid < 64)  s_tb[tid - 32] = tb[tid - 32];
    __syncthreads();

    const int lane = tid & 63, w = tid >> 6;
    const int col0 = lane & 15, q = lane >> 4;

    auto stage = [&](int cc) {
        unsigned short* A = As[cc & 1];
        if (cc < 8) {
#pragma unroll
            for (int i = 0; i < 2; ++i) {
                int lin = tid + 256 * i;
                int row = lin >> 2, seg = lin & 3;
                int node = (cc < 4) ? s_idx[row] : d_idx[row];
                bf16x8 v = *(const bf16x8*)(memb + (size_t)node * 128 + (cc & 3) * 32 + seg * 8);
                *(bf16x8*)&A[row * 40 + seg * 8] = v;
            }
        } else if (cc < 12) {
#pragma unroll
            for (int i = 0; i < 4; ++i) {
                int lin = tid + 256 * i;
                int row = lin >> 3, seg = lin & 7;
                const float4 v = *(const float4*)(raw + (size_t)(e0 + row) * 128 + (cc - 8) * 32 + seg * 4);
                ushort4 o;
                o.x = f2bf(v.x); o.y = f2bf(v.y); o.z = f2bf(v.z); o.w = f2bf(v.w);
                *(ushort4*)&A[row * 40 + seg * 4] = o;
            }
        } else {
            int row = tid >> 1, half = tid & 1;
            float tr = (cc == 12) ? trel_s[e0 + row] : trel_d[e0 + row];
            float f[16];
#pragma unroll
            for (int j2 = 0; j2 < 16; ++j2) {
                int jj = half * 16 + j2;
                f[j2] = __cosf(tr * s_tw[jj] + s_tb[jj]);
            }
            *(bf16x8*)&A[row * 40 + half * 16] = pack8(&f[0]);
            *(bf16x8*)&A[row * 40 + half * 16 + 8] = pack8(&f[8]);
        }
    };

    f32x4 acc[8][4];
#pragma unroll
    for (int a = 0; a < 8; ++a)
#pragma unroll
        for (int b = 0; b < 4; ++b)
#pragma unroll
            for (int i = 0; i < 4; ++i) acc[a][b][i] = 0.0f;

    stage(0);
    __syncthreads();

    for (int c = 0; c < 14; ++c) {
        bf16x8 bfr[4];
        const bf16x8* Wc = (const bf16x8*)Wmf + (size_t)c * 16 * 64;
#pragma unroll
        for (int nl = 0; nl < 4; ++nl)
            bfr[nl] = Wc[(w * 4 + nl) * 64 + lane];
        const unsigned short* A = As[c & 1];
        bf16x8 afr[8];
#pragma unroll
        for (int mt = 0; mt < 8; ++mt)
            afr[mt] = *(const bf16x8*)&A[(mt * 16 + col0) * 40 + q * 8];
        if (c < 13) stage(c + 1);
#pragma unroll
        for (int mt = 0; mt < 8; ++mt)
#pragma unroll
            for (int nl = 0; nl < 4; ++nl)
                acc[mt][nl] = __builtin_amdgcn_mfma_f32_16x16x32_bf16(afr[mt], bfr[nl], acc[mt][nl], 0, 0, 0);
        __syncthreads();
    }

    // epilogue: bias + relu, store to sorted position (C/D: col=lane&15, row=q*4+reg)
#pragma unroll
    for (int nl = 0; nl < 4; ++nl) {
        int j = (w * 4 + nl) * 16 + col0;
        float bv = bm[j];
        int feat = j & 127;
        bool is_s = (j < 128);
#pragma unroll
        for (int mt = 0; mt < 8; ++mt) {
#pragma unroll
            for (int r = 0; r < 4; ++r) {
                int ev = mt * 16 + q * 4 + r;
                float v = fmaxf(acc[mt][nl][r] + bv, 0.0f);
                int pos = is_s ? s_pos[ev] : d_pos[ev];
                msg[(size_t)pos * 128 + feat] = f2bf(v);
            }
        }
    }
}

// ---------------- fused mean-aggregation (sorted, contiguous) + GRU ----------------
// 32 nodes/block, 256 threads. B frags direct from global; no barriers in K-loop.
__launch_bounds__(256, 3)
__global__ void k_gru(const unsigned short* __restrict__ msg,
                      const int* __restrict__ off, const int* __restrict__ cnt,
                      const float* __restrict__ memory,
                      const unsigned short* __restrict__ Wgf,
                      const float* __restrict__ bg,
                      float* __restrict__ out) {
    __shared__ __align__(16) unsigned short Xs[32 * 264];

    const int tid = threadIdx.x;
    const int n0 = blockIdx.x * 32;

    // aggregation: 8 threads/node, 16 feats each; msg rows contiguous per node
    {
        int g = tid >> 3, sub = tid & 7;
        int node = n0 + g;
        int beg = off[node], cn = cnt[node];
        float a[16];
#pragma unroll
        for (int i = 0; i < 16; ++i) a[i] = 0.0f;
        for (int m = 0; m < cn; ++m) {
            const bf16x8* p = (const bf16x8*)(msg + (size_t)(beg + m) * 128 + sub * 16);
            bf16x8 v0 = p[0], v1 = p[1];
#pragma unroll
            for (int k = 0; k < 8; ++k) {
                a[k]     += bf2f((unsigned short)v0[k]);
                a[8 + k] += bf2f((unsigned short)v1[k]);
            }
        }
        float inv = 1.0f / (float)(cn > 1 ? cn : 1);
#pragma unroll
        for (int i = 0; i < 16; ++i) a[i] *= inv;
        *(bf16x8*)&Xs[g * 264 + sub * 16] = pack8(&a[0]);
        *(bf16x8*)&Xs[g * 264 + sub * 16 + 8] = pack8(&a[8]);
        // memory half
        float f[16];
        const float4* mp = (const float4*)(memory + (size_t)node * 128 + sub * 16);
#pragma unroll
        for (int s = 0; s < 4; ++s) {
            float4 v = mp[s];
            f[s * 4 + 0] = v.x; f[s * 4 + 1] = v.y; f[s * 4 + 2] = v.z; f[s * 4 + 3] = v.w;
        }
        *(bf16x8*)&Xs[g * 264 + 128 + sub * 16] = pack8(&f[0]);
        *(bf16x8*)&Xs[g * 264 + 128 + sub * 16 + 8] = pack8(&f[8]);
    }
    __syncthreads();

    const int lane = tid & 63, w = tid >> 6;
    const int col0 = lane & 15, q = lane >> 4;

    f32x4 acc[2][4][2];   // [mt][gate][fh]
#pragma unroll
    for (int a = 0; a < 2; ++a)
#pragma unroll
        for (int g = 0; g < 4; ++g)
#pragma unroll
            for (int f = 0; f < 2; ++f)
#pragma unroll
                for (int i = 0; i < 4; ++i) acc[a][g][f][i] = 0.0f;

#pragma unroll
    for (int c = 0; c < 8; ++c) {
        bf16x8 bfr[4][2];
        const bf16x8* Wc = (const bf16x8*)Wgf + (size_t)c * 32 * 64;
#pragma unroll
        for (int g = 0; g < 4; ++g)
#pragma unroll
            for (int fh = 0; fh < 2; ++fh)
                bfr[g][fh] = Wc[(8 * g + 2 * w + fh) * 64 + lane];
        bf16x8 afr[2];
#pragma unroll
        for (int mt = 0; mt < 2; ++mt)
            afr[mt] = *(const bf16x8*)&Xs[(mt * 16 + col0) * 264 + c * 32 + q * 8];
#pragma unroll
        for (int mt = 0; mt < 2; ++mt)
#pragma unroll
            for (int g = 0; g < 4; ++g)
#pragma unroll
                for (int fh = 0; fh < 2; ++fh)
                    acc[mt][g][fh] = __builtin_amdgcn_mfma_f32_16x16x32_bf16(afr[mt], bfr[g][fh], acc[mt][g][fh], 0, 0, 0);
    }

    // epilogue: gates + blend
#pragma unroll
    for (int fh = 0; fh < 2; ++fh) {
        int feat = w * 32 + fh * 16 + col0;
        float b_r = bg[feat], b_z = bg[128 + feat], b_in = bg[256 + feat], b_hn = bg[384 + feat];
#pragma unroll
        for (int mt = 0; mt < 2; ++mt) {
#pragma unroll
            for (int r = 0; r < 4; ++r) {
                int node = n0 + mt * 16 + q * 4 + r;
                float rr = sigmoidf_(acc[mt][0][fh][r] + b_r);
                float zz = sigmoidf_(acc[mt][1][fh][r] + b_z);
                float nn = tanhf_((acc[mt][2][fh][r] + b_in) + rr * (acc[mt][3][fh][r] + b_hn));
                float h = memory[(size_t)node * 128 + feat];
                out[(size_t)node * 128 + feat] = (1.0f - zz) * nn + zz * h;
            }
        }
    }
}

// ---------------- last_update -> float output ----------------
__global__ void k_lu(const int* __restrict__ lu_tmp, float* __restrict__ outp) {
    int i = blockIdx.x * 256 + threadIdx.x;
    outp[i] = (float)lu_tmp[i];
}

extern "C" void kernel_launch(void* const* d_in, const int* in_sizes, int n_in,
                              void* d_out, int out_size, void* d_ws, size_t ws_size,
                              hipStream_t stream) {
    const float* memory = (const float*)d_in[0];
    const float* raw    = (const float*)d_in[1];
    const float* tw     = (const float*)d_in[2];
    const float* tb     = (const float*)d_in[3];
    const float* Wms    = (const float*)d_in[4];
    const float* bms    = (const float*)d_in[5];
    const float* Wmd    = (const float*)d_in[6];
    const float* bmd    = (const float*)d_in[7];
    const float* Wih    = (const float*)d_in[8];
    const float* Whh    = (const float*)d_in[9];
    const float* bih    = (const float*)d_in[10];
    const float* bhh    = (const float*)d_in[11];
    const int* src = (const int*)d_in[12];
    const int* dst = (const int*)d_in[13];
    const int* t   = (const int*)d_in[14];
    const int* lu  = (const int*)d_in[15];

    char* ws = (char*)d_ws;
    size_t ob = 0;
    unsigned short* memb = (unsigned short*)(ws + ob); ob += (size_t)NN * 128 * 2;       // 32 MB
    unsigned short* msg  = (unsigned short*)(ws + ob); ob += (size_t)2 * EE * 128 * 2;   // 128 MB (sorted)
    float* trel_s        = (float*)(ws + ob);          ob += (size_t)EE * 4;
    float* trel_d        = (float*)(ws + ob);          ob += (size_t)EE * 4;
    int* cnt             = (int*)(ws + ob);            ob += (size_t)NN * 4;
    int* off             = (int*)(ws + ob);            ob += (size_t)NN * 4;
    int* cursor          = (int*)(ws + ob);            ob += (size_t)NN * 4;
    int* lu_tmp          = (int*)(ws + ob);            ob += (size_t)NN * 4;
    int* pos2            = (int*)(ws + ob);            ob += (size_t)2 * EE * 4;         // 2 MB
    int* bsum            = (int*)(ws + ob);            ob += 512 * 4;
    int* boff            = (int*)(ws + ob);            ob += 512 * 4;
    unsigned short* Wmf  = (unsigned short*)(ws + ob); ob += (size_t)14 * 16 * 64 * 8 * 2;
    float* bm            = (float*)(ws + ob);          ob += 256 * 4;
    unsigned short* Wgf  = (unsigned short*)(ws + ob); ob += (size_t)8 * 32 * 64 * 8 * 2;
    float* bg            = (float*)(ws + ob);          ob += 512 * 4;

    float* out = (float*)d_out;

    hipMemsetAsync(cnt, 0, (size_t)NN * 4, stream);
    hipMemsetAsync(lu_tmp, 0, (size_t)NN * 4, stream);

    k_prep_msgfrag<<<14 * 16, 64, 0, stream>>>(Wms, Wmd, bms, bmd, Wmf, bm);
    k_prep_grufrag<<<8 * 32, 64, 0, stream>>>(Wih, Whh, bih, bhh, Wgf, bg);
    k_memconv<<<(NN * 128 / 4) / 256, 256, 0, stream>>>(memory, memb);
    k_pre<<<EE / 256, 256, 0, stream>>>(t, src, dst, lu, trel_s, trel_d, cnt, lu_tmp);
    k_scan1<<<512, 256, 0, stream>>>(cnt, bsum);
    k_scan2<<<1, 512, 0, stream>>>(bsum, boff);
    k_scan3<<<512, 256, 0, stream>>>(cnt, boff, off, cursor);
    k_fill<<<2 * EE / 256, 256, 0, stream>>>(src, dst, cursor, pos2);
    k_msg<<<EE / 128, 256, 0, stream>>>(memb, raw, trel_s, trel_d, Wmf, bm, src, dst, pos2, tw, tb, msg);
    k_gru<<<NN / 32, 256, 0, stream>>>(msg, off, cnt, memory, Wgf, bg, out);
    k_lu<<<NN / 256, 256, 0, stream>>>(lu_tmp, out + (size_t)NN * 128);
}